// Round 1
// baseline (123.179 us; speedup 1.0000x reference)
//
#include <hip/hip_runtime.h>

#define B_    1
#define N_    6
#define C_    80
#define D_    112
#define HF_   16
#define WF_   44
#define NX_   128
#define NY_   128
#define NZ_   1
#define BN_   (B_ * N_)
#define HW_   (HF_ * WF_)
#define NPIX_ (NZ_ * NX_ * NY_)

// ---------------- 3x3 inverse (adjugate) ----------------
__device__ __forceinline__ void inv3(const float* m, float* o) {
    float a = m[0], b = m[1], c = m[2];
    float d = m[3], e = m[4], f = m[5];
    float g = m[6], h = m[7], i = m[8];
    float A  =  (e * i - f * h);
    float Bc = -(d * i - f * g);
    float Cc =  (d * h - e * g);
    float det = a * A + b * Bc + c * Cc;
    float id = 1.0f / det;
    o[0] = A * id;                  o[1] = -(b * i - c * h) * id;   o[2] =  (b * f - c * e) * id;
    o[3] = Bc * id;                 o[4] =  (a * i - c * g) * id;   o[5] = -(a * f - c * d) * id;
    o[6] = Cc * id;                 o[7] = -(a * h - b * g) * id;   o[8] =  (a * e - b * d) * id;
}

// mats layout per bn (24 floats): invPost[9], combine[9], post_trans[3], trans[3]
__global__ void prep_mats_kernel(const float* __restrict__ rots,
                                 const float* __restrict__ trans,
                                 const float* __restrict__ intrins,
                                 const float* __restrict__ post_rots,
                                 const float* __restrict__ post_trans,
                                 float* __restrict__ mats) {
    int bn = threadIdx.x;
    if (bn >= BN_) return;
    float ip[9], ii[9];
    inv3(post_rots + bn * 9, ip);
    inv3(intrins + bn * 9, ii);
    const float* ro = rots + bn * 9;
    float* out = mats + bn * 24;
    #pragma unroll
    for (int r = 0; r < 3; ++r)
        #pragma unroll
        for (int c = 0; c < 3; ++c)
            out[9 + r * 3 + c] = ro[r * 3 + 0] * ii[0 * 3 + c] +
                                 ro[r * 3 + 1] * ii[1 * 3 + c] +
                                 ro[r * 3 + 2] * ii[2 * 3 + c];
    #pragma unroll
    for (int k = 0; k < 9; ++k) out[k] = ip[k];
    #pragma unroll
    for (int k = 0; k < 3; ++k) { out[18 + k] = post_trans[bn * 3 + k]; out[21 + k] = trans[bn * 3 + k]; }
}

// one block (128 threads) per (bn, h, w) pixel
// mode 0: scatter directly into out layout (b, c, iz, ix, iy)
// mode 1: scatter into tmp layout (b, iz, ix, iy, c)  [contiguous channels]
__global__ __launch_bounds__(128) void scatter_kernel(const float* __restrict__ img_feat,
                                                      const float* __restrict__ depth_digit,
                                                      const float* __restrict__ mats,
                                                      float* __restrict__ outp,
                                                      int mode) {
    int blk = blockIdx.x;
    int w  = blk % WF_;
    int h  = (blk / WF_) % HF_;
    int bn = blk / HW_;
    int b  = bn / N_;
    int tid = threadIdx.x;

    __shared__ float sm[24];
    __shared__ float s_feat[C_];
    __shared__ float s_prob[D_];
    __shared__ int   s_vox[D_];
    __shared__ float s_red[128];
    __shared__ float s_mw[D_];
    __shared__ int   s_mvox[D_];
    __shared__ int   s_cnt;

    if (tid < 24) sm[tid] = mats[bn * 24 + tid];
    if (tid < C_) s_feat[tid] = img_feat[((size_t)bn * C_ + tid) * HW_ + h * WF_ + w];

    float logit = -INFINITY;
    if (tid < D_) logit = depth_digit[((size_t)bn * D_ + tid) * HW_ + h * WF_ + w];
    s_red[tid] = logit;
    __syncthreads();
    #pragma unroll
    for (int s = 64; s > 0; s >>= 1) {
        if (tid < s) s_red[tid] = fmaxf(s_red[tid], s_red[tid + s]);
        __syncthreads();
    }
    float mx = s_red[0];
    __syncthreads();
    float e = (tid < D_) ? __expf(logit - mx) : 0.0f;
    s_red[tid] = e;
    __syncthreads();
    #pragma unroll
    for (int s = 64; s > 0; s >>= 1) {
        if (tid < s) s_red[tid] += s_red[tid + s];
        __syncthreads();
    }
    float inv_sum = 1.0f / s_red[0];
    if (tid < D_) s_prob[tid] = e * inv_sum;

    // geometry: voxel index per depth bin
    if (tid < D_) {
        float dval = 2.0f + 0.5f * (float)tid;
        float xs = (float)((double)w * (703.0 / 43.0));  // linspace(0, 703, 44)
        float ys = (float)((double)h * 17.0);            // linspace(0, 255, 16)
        const float* ip  = sm;
        const float* cmb = sm + 9;
        const float* pt  = sm + 18;
        const float* tr  = sm + 21;
        float p0x = xs - pt[0], p0y = ys - pt[1], p0z = dval - pt[2];
        float p1x = ip[0] * p0x + ip[1] * p0y + ip[2] * p0z;
        float p1y = ip[3] * p0x + ip[4] * p0y + ip[5] * p0z;
        float p1z = ip[6] * p0x + ip[7] * p0y + ip[8] * p0z;
        float qx = p1x * p1z, qy = p1y * p1z, qz = p1z;
        float rx = cmb[0] * qx + cmb[1] * qy + cmb[2] * qz + tr[0];
        float ry = cmb[3] * qx + cmb[4] * qy + cmb[5] * qz + tr[1];
        float rz = cmb[6] * qx + cmb[7] * qy + cmb[8] * qz + tr[2];
        const float lox = -50.8f - 0.4f;   // bx - dx/2 in f32, compile-time f32 fold
        const float loy = -50.8f - 0.4f;
        const float loz = 0.0f - 10.0f;
        int ix = (int)((rx - lox) / 0.8f);   // trunc toward zero == astype(int32)
        int iy = (int)((ry - loy) / 0.8f);
        int iz = (int)((rz - loz) / 20.0f);
        bool val = (ix >= 0) && (ix < NX_) && (iy >= 0) && (iy < NY_) && (iz >= 0) && (iz < NZ_);
        s_vox[tid] = val ? ((iz * NX_ + ix) * NY_ + iy) : -1;
    }
    __syncthreads();

    // run-length merge consecutive depth bins hitting the same voxel
    if (tid == 0) {
        int cnt = 0, last = -1;
        float wsum = 0.0f;
        for (int d0 = 0; d0 < D_; ++d0) {
            int v = s_vox[d0];
            if (v < 0) continue;
            if (v == last) {
                wsum += s_prob[d0];
            } else {
                if (last >= 0) { s_mvox[cnt] = last; s_mw[cnt] = wsum; ++cnt; }
                last = v; wsum = s_prob[d0];
            }
        }
        if (last >= 0) { s_mvox[cnt] = last; s_mw[cnt] = wsum; ++cnt; }
        s_cnt = cnt;
    }
    __syncthreads();

    int cnt = s_cnt;
    int total = cnt * C_;
    for (int k = tid; k < total; k += 128) {
        int i = k / C_;
        int c = k - i * C_;
        int pix = s_mvox[i];
        float v = s_mw[i] * s_feat[c];
        float* addr;
        if (mode) addr = outp + ((size_t)b * NPIX_ + pix) * C_ + c;
        else      addr = outp + ((size_t)(b * C_ + c)) * NPIX_ + pix;
        atomicAdd(addr, v);
    }
}

// tmp (b, pix, c) -> out (b, c, pix); writes every out element (covers poison)
__global__ __launch_bounds__(256) void transpose_kernel(const float* __restrict__ tmp,
                                                        float* __restrict__ outp) {
    size_t idx = (size_t)blockIdx.x * 256 + threadIdx.x;
    const size_t total = (size_t)B_ * C_ * NPIX_;
    if (idx >= total) return;
    int pix = (int)(idx % NPIX_);
    int c   = (int)((idx / NPIX_) % C_);
    int b   = (int)(idx / ((size_t)C_ * NPIX_));
    outp[idx] = tmp[((size_t)b * NPIX_ + pix) * C_ + c];
}

extern "C" void kernel_launch(void* const* d_in, const int* in_sizes, int n_in,
                              void* d_out, int out_size, void* d_ws, size_t ws_size,
                              hipStream_t stream) {
    const float* rots        = (const float*)d_in[1];
    const float* trans       = (const float*)d_in[2];
    const float* intrins     = (const float*)d_in[3];
    const float* post_rots   = (const float*)d_in[4];
    const float* post_trans  = (const float*)d_in[5];
    const float* img_feat    = (const float*)d_in[6];
    const float* depth_digit = (const float*)d_in[7];
    float* outp = (float*)d_out;

    float* mats = (float*)d_ws;
    const size_t matBytes = (size_t)BN_ * 24 * sizeof(float);
    const size_t tmpBytes = (size_t)B_ * NPIX_ * C_ * sizeof(float);
    float* tmp = (float*)((char*)d_ws + matBytes);
    bool useTmp = (ws_size >= matBytes + tmpBytes);

    prep_mats_kernel<<<1, 64, 0, stream>>>(rots, trans, intrins, post_rots, post_trans, mats);

    if (useTmp) {
        hipMemsetAsync(tmp, 0, tmpBytes, stream);
        scatter_kernel<<<BN_ * HW_, 128, 0, stream>>>(img_feat, depth_digit, mats, tmp, 1);
        const size_t total = (size_t)B_ * C_ * NPIX_;
        transpose_kernel<<<(int)((total + 255) / 256), 256, 0, stream>>>(tmp, outp);
    } else {
        hipMemsetAsync(outp, 0, (size_t)out_size * sizeof(float), stream);
        scatter_kernel<<<BN_ * HW_, 128, 0, stream>>>(img_feat, depth_digit, mats, outp, 0);
    }
}